// Round 3
// baseline (186.420 us; speedup 1.0000x reference)
//
#include <hip/hip_runtime.h>

#define NN 256

// hard-coded CG constants (l<=2), float32
#define C13  0.5773502691896258f   // 1/sqrt(3)
#define C15  0.4472135954999579f   // 1/sqrt(5)
#define CC12 0.7071067811865476f   // 1/sqrt(2)
#define S35  0.7745966692414834f   // sqrt(3/5)
#define S310 0.5477225575051661f   // sqrt(3/10)
#define C110 0.3162277660168379f   // 1/sqrt(10)
#define S25  0.6324555320336759f   // sqrt(2/5)
#define S23  0.8164965809277260f   // sqrt(2/3)
#define C16  0.4082482904638630f   // 1/sqrt(6)
#define S27  0.5345224838248488f   // sqrt(2/7)
#define S37  0.6546536707079771f   // sqrt(3/7)
#define C114 0.2672612419124244f   // 1/sqrt(14)

// Per-lane CG contraction for one (x-column mx[9], y-column sv[9]) pair.
// r0[3]: L=0 chunks (0,0),(1,1),(2,2)
// r1[3][6]: L=1, M=0..2, chunks (0,1),(1,0),(1,1),(1,2),(2,1),(2,2)
// r2[5][6]: L=2, M=0..4, chunks (0,2),(1,1),(1,2),(2,0),(2,1),(2,2)
#define CGREL(mx, sv, r0, r1, r2) \
    r0[0] = mx[0]*sv[0]; \
    r0[1] = C13*(mx[1]*sv[3] - mx[2]*sv[2] + mx[3]*sv[1]); \
    r0[2] = C15*(mx[4]*sv[8] - mx[5]*sv[7] + mx[6]*sv[6] - mx[7]*sv[5] + mx[8]*sv[4]); \
    r1[0][0] = mx[0]*sv[1]; r1[1][0] = mx[0]*sv[2]; r1[2][0] = mx[0]*sv[3]; \
    r1[0][1] = mx[1]*sv[0]; r1[1][1] = mx[2]*sv[0]; r1[2][1] = mx[3]*sv[0]; \
    r1[0][2] = CC12*(mx[2]*sv[1] - mx[1]*sv[2]); \
    r1[1][2] = CC12*(mx[3]*sv[1] - mx[1]*sv[3]); \
    r1[2][2] = CC12*(mx[3]*sv[2] - mx[2]*sv[3]); \
    r1[0][3] = S35*mx[3]*sv[4] - S310*mx[2]*sv[5] + C110*mx[1]*sv[6]; \
    r1[1][3] = S310*(mx[3]*sv[5] + mx[1]*sv[7]) - S25*mx[2]*sv[6]; \
    r1[2][3] = S35*mx[1]*sv[8] - S310*mx[2]*sv[7] + C110*mx[3]*sv[6]; \
    r1[0][4] = C110*mx[6]*sv[1] - S310*mx[5]*sv[2] + S35*mx[4]*sv[3]; \
    r1[1][4] = S310*(mx[7]*sv[1] + mx[5]*sv[3]) - S25*mx[6]*sv[2]; \
    r1[2][4] = S35*mx[8]*sv[1] - S310*mx[7]*sv[2] + C110*mx[6]*sv[3]; \
    r1[0][5] = C15*(mx[7]*sv[4] - mx[4]*sv[7]) + S310*(mx[5]*sv[6] - mx[6]*sv[5]); \
    r1[1][5] = S25*(mx[8]*sv[4] - mx[4]*sv[8]) + C110*(mx[5]*sv[7] - mx[7]*sv[5]); \
    r1[2][5] = C15*(mx[8]*sv[5] - mx[5]*sv[8]) + S310*(mx[6]*sv[7] - mx[7]*sv[6]); \
    r2[0][0]=mx[0]*sv[4]; r2[1][0]=mx[0]*sv[5]; r2[2][0]=mx[0]*sv[6]; r2[3][0]=mx[0]*sv[7]; r2[4][0]=mx[0]*sv[8]; \
    r2[0][1] = mx[1]*sv[1]; \
    r2[1][1] = CC12*(mx[2]*sv[1] + mx[1]*sv[2]); \
    r2[2][1] = C16*(mx[3]*sv[1] + mx[1]*sv[3]) + S23*mx[2]*sv[2]; \
    r2[3][1] = CC12*(mx[3]*sv[2] + mx[2]*sv[3]); \
    r2[4][1] = mx[3]*sv[3]; \
    r2[0][2] = S23*mx[2]*sv[4] - C13*mx[1]*sv[5]; \
    r2[1][2] = C13*mx[3]*sv[4] + C16*mx[2]*sv[5] - CC12*mx[1]*sv[6]; \
    r2[2][2] = CC12*(mx[3]*sv[5] - mx[1]*sv[7]); \
    r2[3][2] = CC12*mx[3]*sv[6] - C16*mx[2]*sv[7] - C13*mx[1]*sv[8]; \
    r2[4][2] = C13*mx[3]*sv[7] - S23*mx[2]*sv[8]; \
    r2[0][3]=mx[4]*sv[0]; r2[1][3]=mx[5]*sv[0]; r2[2][3]=mx[6]*sv[0]; r2[3][3]=mx[7]*sv[0]; r2[4][3]=mx[8]*sv[0]; \
    r2[0][4] = C13*mx[5]*sv[1] - S23*mx[4]*sv[2]; \
    r2[1][4] = CC12*mx[6]*sv[1] - C16*mx[5]*sv[2] - C13*mx[4]*sv[3]; \
    r2[2][4] = CC12*(mx[7]*sv[1] - mx[5]*sv[3]); \
    r2[3][4] = C13*mx[8]*sv[1] + C16*mx[7]*sv[2] - CC12*mx[6]*sv[3]; \
    r2[4][4] = S23*mx[8]*sv[2] - C13*mx[7]*sv[3]; \
    r2[0][5] = S27*(mx[4]*sv[6] + mx[6]*sv[4]) - S37*mx[5]*sv[5]; \
    r2[1][5] = S37*(mx[4]*sv[7] + mx[7]*sv[4]) - C114*(mx[5]*sv[6] + mx[6]*sv[5]); \
    r2[2][5] = S27*(mx[8]*sv[4] + mx[4]*sv[8] - mx[6]*sv[6]) + C114*(mx[7]*sv[5] + mx[5]*sv[7]); \
    r2[3][5] = S37*(mx[8]*sv[5] + mx[5]*sv[8]) - C114*(mx[7]*sv[6] + mx[6]*sv[7]); \
    r2[4][5] = S27*(mx[8]*sv[6] + mx[6]*sv[8]) - S37*mx[7]*sv[7];

// ---------------- kernel A: vmp + node-CG + wn mix -> mixed[256][72] -------
// One wave per node. Lane = (c,d) = (lane>>3, lane&7).
__global__ void k_nodes(const float* __restrict__ adj,
                        const float* __restrict__ v0,
                        const float* __restrict__ v1,
                        const float* __restrict__ v2,
                        const float* __restrict__ wn0,
                        const float* __restrict__ wn1,
                        const float* __restrict__ wn2,
                        float* __restrict__ mixed){
  __shared__ float vb[72];
  int i = blockIdx.x;
  int lane = threadIdx.x;

  // ---- vmp row i: vb[t] = sum_j adj[i,j] * v[j, t] ----
  {
    const float* vp1; int st1;
    if (lane < 8)       { vp1 = v0 + lane;      st1 = 8;  }
    else if (lane < 32) { vp1 = v1 + (lane-8);  st1 = 24; }
    else                { vp1 = v2 + (lane-32); st1 = 40; }
    const float* vp2 = v2 + 32 + lane;   // valid only for lane<8 (t = 64+lane)
    const float* arow = adj + i*NN;
    float a1a = 0.f, a1b = 0.f, a2a = 0.f, a2b = 0.f;
    #pragma unroll 4
    for (int j = 0; j < NN; j += 2){
      float av0 = arow[j], av1 = arow[j+1];
      a1a = fmaf(av0, vp1[j*st1], a1a);
      a1b = fmaf(av1, vp1[(j+1)*st1], a1b);
      if (lane < 8){
        a2a = fmaf(av0, vp2[j*40], a2a);
        a2b = fmaf(av1, vp2[(j+1)*40], a2b);
      }
    }
    vb[lane] = a1a + a1b;
    if (lane < 8) vb[64+lane] = a2a + a2b;
  }
  __syncthreads();

  // ---- per-lane CG(vb_col_c, vb_col_d) ----
  int c = lane >> 3, d = lane & 7;
  float mx[9], sv[9];
  #pragma unroll
  for (int j=0;j<9;j++){ mx[j] = vb[j*8 + c]; sv[j] = vb[j*8 + d]; }
  float r0[3], r1[3][6], r2[5][6];
  CGREL(mx, sv, r0, r1, r2)

  // ---- wn contraction: out[mall][dp] = sum_{lane,chunk} r * wn[chunk*64+lane][dp]
  float a0[8], a1m[3][8], a2m[5][8];
  #pragma unroll
  for (int dp=0;dp<8;dp++){ a0[dp]=0.f;
    #pragma unroll
    for (int M=0;M<3;M++) a1m[M][dp]=0.f;
    #pragma unroll
    for (int M=0;M<5;M++) a2m[M][dp]=0.f;
  }
  #pragma unroll
  for (int k=0;k<3;k++){
    const float* row = wn0 + (k*64 + lane)*8;
    float4 u = *(const float4*)row;
    float4 v = *(const float4*)(row+4);
    float u8[8] = {u.x,u.y,u.z,u.w,v.x,v.y,v.z,v.w};
    #pragma unroll
    for (int dp=0;dp<8;dp++) a0[dp] = fmaf(r0[k], u8[dp], a0[dp]);
  }
  #pragma unroll
  for (int k=0;k<6;k++){
    const float* row = wn1 + (k*64 + lane)*8;
    float4 u = *(const float4*)row;
    float4 v = *(const float4*)(row+4);
    float u8[8] = {u.x,u.y,u.z,u.w,v.x,v.y,v.z,v.w};
    #pragma unroll
    for (int M=0;M<3;M++)
      #pragma unroll
      for (int dp=0;dp<8;dp++) a1m[M][dp] = fmaf(r1[M][k], u8[dp], a1m[M][dp]);
  }
  #pragma unroll
  for (int k=0;k<6;k++){
    const float* row = wn2 + (k*64 + lane)*8;
    float4 u = *(const float4*)row;
    float4 v = *(const float4*)(row+4);
    float u8[8] = {u.x,u.y,u.z,u.w,v.x,v.y,v.z,v.w};
    #pragma unroll
    for (int M=0;M<5;M++)
      #pragma unroll
      for (int dp=0;dp<8;dp++) a2m[M][dp] = fmaf(r2[M][k], u8[dp], a2m[M][dp]);
  }

  // ---- reduce over 64 lanes, write mixed[i][mall*8+dp] ----
  #pragma unroll
  for (int m=0;m<9;m++){
    #pragma unroll
    for (int dp=0;dp<8;dp++){
      float val = (m==0) ? a0[dp] : (m<4 ? a1m[m-1][dp] : a2m[m-4][dp]);
      val += __shfl_xor(val, 1);
      val += __shfl_xor(val, 2);
      val += __shfl_xor(val, 4);
      val += __shfl_xor(val, 8);
      val += __shfl_xor(val, 16);
      val += __shfl_xor(val, 32);
      if (lane == ((m*8+dp) & 63)) mixed[i*72 + m*8 + dp] = val;
    }
  }
}

// ---------------- kernel B: pairwise CG(mixed,s) + wr mix, sum over x ------
// 2048 blocks x 4 waves; all 4 waves share y, xbase differs -> block reduce.
#define XPW 8
__global__ __launch_bounds__(256, 8) void k_pair(
    const float* __restrict__ mixed,
    const float* __restrict__ s0, const float* __restrict__ s1, const float* __restrict__ s2,
    const float* __restrict__ wr0, const float* __restrict__ wr1, const float* __restrict__ wr2,
    float* __restrict__ vsum){
  __shared__ float red[4][72];
  int tid = threadIdx.x;
  int wave = tid >> 6, lane = tid & 63;
  int y = blockIdx.x & (NN-1);
  int xsel = blockIdx.x >> 8;              // 0..7
  int xbase = (xsel*4 + wave) * XPW;
  int cgp = lane >> 3;

  float acc[9];
  #pragma unroll
  for (int m=0;m<9;m++) acc[m]=0.f;

  float mx[9], sv[9];
  {
    const float* mb = mixed + xbase*72 + cgp;
    #pragma unroll
    for (int j=0;j<9;j++) mx[j] = mb[j*8];
    int pxy = xbase*NN + y;
    sv[0] = s0[pxy];
    #pragma unroll
    for (int j=0;j<3;j++) sv[1+j] = s1[pxy*3+j];
    #pragma unroll
    for (int j=0;j<5;j++) sv[4+j] = s2[pxy*5+j];
  }

  for (int i=0;i<XPW;i++){
    int x = xbase + i;
    int pxy = x*NN + y;
    // issue wr loads early (consumed ~200 VALU ops later)
    const float* p0 = wr0 + pxy*192 + lane;
    const float* p1 = wr1 + pxy*384 + lane;
    const float* p2 = wr2 + pxy*384 + lane;
    float w0[3], w1[6], w2[6];
    #pragma unroll
    for (int k=0;k<3;k++) w0[k] = p0[k*64];
    #pragma unroll
    for (int k=0;k<6;k++) w1[k] = p1[k*64];
    #pragma unroll
    for (int k=0;k<6;k++) w2[k] = p2[k*64];

    // prefetch next pair's mixed/s
    float nmx[9], nsv[9];
    {
      int xn = x + ((i < XPW-1) ? 1 : 0);
      const float* mb = mixed + xn*72 + cgp;
      #pragma unroll
      for (int j=0;j<9;j++) nmx[j] = mb[j*8];
      int pn = xn*NN + y;
      nsv[0] = s0[pn];
      #pragma unroll
      for (int j=0;j<3;j++) nsv[1+j] = s1[pn*3+j];
      #pragma unroll
      for (int j=0;j<5;j++) nsv[4+j] = s2[pn*5+j];
    }

    float r0[3], r1[3][6], r2[5][6];
    CGREL(mx, sv, r0, r1, r2)

    // ---- FMA with wr ----
    #pragma unroll
    for (int k=0;k<3;k++) acc[0] = fmaf(r0[k], w0[k], acc[0]);
    #pragma unroll
    for (int k=0;k<6;k++){
      acc[1] = fmaf(r1[0][k], w1[k], acc[1]);
      acc[2] = fmaf(r1[1][k], w1[k], acc[2]);
      acc[3] = fmaf(r1[2][k], w1[k], acc[3]);
      acc[4] = fmaf(r2[0][k], w2[k], acc[4]);
      acc[5] = fmaf(r2[1][k], w2[k], acc[5]);
      acc[6] = fmaf(r2[2][k], w2[k], acc[6]);
      acc[7] = fmaf(r2[3][k], w2[k], acc[7]);
      acc[8] = fmaf(r2[4][k], w2[k], acc[8]);
    }
    #pragma unroll
    for (int j=0;j<9;j++){ mx[j]=nmx[j]; sv[j]=nsv[j]; }
  }

  // reduce over cgp groups (lane bits 3..5)
  #pragma unroll
  for (int m=0;m<9;m++){
    float v = acc[m];
    v += __shfl_xor(v, 8);
    v += __shfl_xor(v, 16);
    v += __shfl_xor(v, 32);
    acc[m] = v;
  }
  if (lane < 8){
    #pragma unroll
    for (int m=0;m<9;m++) red[wave][m*8+lane] = acc[m];
  }
  __syncthreads();
  if (tid < 72){
    float v = red[0][tid] + red[1][tid] + red[2][tid] + red[3][tid];
    atomicAdd(&vsum[y*72 + tid], v);
  }
}

// ---------------- kernel C: part sums + normalize + write ------------------
__global__ void k_final(const float* __restrict__ vsum, float* __restrict__ out){
  __shared__ float ps[3];
  int t = threadIdx.x;   // 1024 threads; 18 elements each
  if (t < 3) ps[t] = 0.f;
  __syncthreads();
  float vals[18];
  float p0=0.f, p1=0.f, p2=0.f;
  #pragma unroll
  for (int k=0;k<18;k++){
    int idx = t*18 + k;
    float v = vsum[idx];
    vals[k] = v;
    int mall = (idx >> 3) % 9;
    if (mall == 0) p0 += v; else if (mall < 4) p1 += v; else p2 += v;
  }
  // wave reduce then LDS atomic
  #pragma unroll
  for (int s=1; s<64; s<<=1){
    p0 += __shfl_xor(p0, s);
    p1 += __shfl_xor(p1, s);
    p2 += __shfl_xor(p2, s);
  }
  if ((t & 63) == 0){
    atomicAdd(&ps[0], p0);
    atomicAdd(&ps[1], p1);
    atomicAdd(&ps[2], p2);
  }
  __syncthreads();
  float q0 = ps[0], q1 = ps[1], q2 = ps[2];
  #pragma unroll
  for (int k=0;k<18;k++){
    int idx = t*18 + k;
    int mall = (idx >> 3) % 9;
    float den = (mall == 0) ? q0 : (mall < 4 ? q1 : q2);
    out[idx] = vals[k] / den;
  }
}

extern "C" void kernel_launch(void* const* d_in, const int* in_sizes, int n_in,
                              void* d_out, int out_size, void* d_ws, size_t ws_size,
                              hipStream_t stream) {
  const float* v0  = (const float*)d_in[0];
  const float* v1  = (const float*)d_in[1];
  const float* v2  = (const float*)d_in[2];
  const float* adj = (const float*)d_in[3];
  const float* s0  = (const float*)d_in[4];
  const float* s1  = (const float*)d_in[5];
  const float* s2  = (const float*)d_in[6];
  const float* wn0 = (const float*)d_in[7];
  const float* wn1 = (const float*)d_in[8];
  const float* wn2 = (const float*)d_in[9];
  const float* wr0 = (const float*)d_in[10];
  const float* wr1 = (const float*)d_in[11];
  const float* wr2 = (const float*)d_in[12];
  float* out = (float*)d_out;

  float* ws    = (float*)d_ws;
  float* mixed = ws;            // 18432
  float* vsum  = ws + 18432;    // 18432

  hipMemsetAsync(vsum, 0, 18432*sizeof(float), stream);
  k_nodes<<<NN, 64, 0, stream>>>(adj, v0, v1, v2, wn0, wn1, wn2, mixed);
  k_pair<<<NN*8, 256, 0, stream>>>(mixed, s0, s1, s2, wr0, wr1, wr2, vsum);
  k_final<<<1, 1024, 0, stream>>>(vsum, out);
}

// Round 4
// 120.484 us; speedup vs baseline: 1.5473x; 1.5473x over previous
//
#include <hip/hip_runtime.h>

#define NN 256

// hard-coded CG constants (l<=2), float32
#define C13  0.5773502691896258f   // 1/sqrt(3)
#define C15  0.4472135954999579f   // 1/sqrt(5)
#define CC12 0.7071067811865476f   // 1/sqrt(2)
#define S35  0.7745966692414834f   // sqrt(3/5)
#define S310 0.5477225575051661f   // sqrt(3/10)
#define C110 0.3162277660168379f   // 1/sqrt(10)
#define S25  0.6324555320336759f   // sqrt(2/5)
#define S23  0.8164965809277260f   // sqrt(2/3)
#define C16  0.4082482904638630f   // 1/sqrt(6)
#define S27  0.5345224838248488f   // sqrt(2/7)
#define S37  0.6546536707079771f   // sqrt(3/7)
#define C114 0.2672612419124244f   // 1/sqrt(14)

// Per-lane CG contraction for one (x-column mx[9], y-column sv[9]) pair.
#define CGREL(mx, sv, r0, r1, r2) \
    r0[0] = mx[0]*sv[0]; \
    r0[1] = C13*(mx[1]*sv[3] - mx[2]*sv[2] + mx[3]*sv[1]); \
    r0[2] = C15*(mx[4]*sv[8] - mx[5]*sv[7] + mx[6]*sv[6] - mx[7]*sv[5] + mx[8]*sv[4]); \
    r1[0][0] = mx[0]*sv[1]; r1[1][0] = mx[0]*sv[2]; r1[2][0] = mx[0]*sv[3]; \
    r1[0][1] = mx[1]*sv[0]; r1[1][1] = mx[2]*sv[0]; r1[2][1] = mx[3]*sv[0]; \
    r1[0][2] = CC12*(mx[2]*sv[1] - mx[1]*sv[2]); \
    r1[1][2] = CC12*(mx[3]*sv[1] - mx[1]*sv[3]); \
    r1[2][2] = CC12*(mx[3]*sv[2] - mx[2]*sv[3]); \
    r1[0][3] = S35*mx[3]*sv[4] - S310*mx[2]*sv[5] + C110*mx[1]*sv[6]; \
    r1[1][3] = S310*(mx[3]*sv[5] + mx[1]*sv[7]) - S25*mx[2]*sv[6]; \
    r1[2][3] = S35*mx[1]*sv[8] - S310*mx[2]*sv[7] + C110*mx[3]*sv[6]; \
    r1[0][4] = C110*mx[6]*sv[1] - S310*mx[5]*sv[2] + S35*mx[4]*sv[3]; \
    r1[1][4] = S310*(mx[7]*sv[1] + mx[5]*sv[3]) - S25*mx[6]*sv[2]; \
    r1[2][4] = S35*mx[8]*sv[1] - S310*mx[7]*sv[2] + C110*mx[6]*sv[3]; \
    r1[0][5] = C15*(mx[7]*sv[4] - mx[4]*sv[7]) + S310*(mx[5]*sv[6] - mx[6]*sv[5]); \
    r1[1][5] = S25*(mx[8]*sv[4] - mx[4]*sv[8]) + C110*(mx[5]*sv[7] - mx[7]*sv[5]); \
    r1[2][5] = C15*(mx[8]*sv[5] - mx[5]*sv[8]) + S310*(mx[6]*sv[7] - mx[7]*sv[6]); \
    r2[0][0]=mx[0]*sv[4]; r2[1][0]=mx[0]*sv[5]; r2[2][0]=mx[0]*sv[6]; r2[3][0]=mx[0]*sv[7]; r2[4][0]=mx[0]*sv[8]; \
    r2[0][1] = mx[1]*sv[1]; \
    r2[1][1] = CC12*(mx[2]*sv[1] + mx[1]*sv[2]); \
    r2[2][1] = C16*(mx[3]*sv[1] + mx[1]*sv[3]) + S23*mx[2]*sv[2]; \
    r2[3][1] = CC12*(mx[3]*sv[2] + mx[2]*sv[3]); \
    r2[4][1] = mx[3]*sv[3]; \
    r2[0][2] = S23*mx[2]*sv[4] - C13*mx[1]*sv[5]; \
    r2[1][2] = C13*mx[3]*sv[4] + C16*mx[2]*sv[5] - CC12*mx[1]*sv[6]; \
    r2[2][2] = CC12*(mx[3]*sv[5] - mx[1]*sv[7]); \
    r2[3][2] = CC12*mx[3]*sv[6] - C16*mx[2]*sv[7] - C13*mx[1]*sv[8]; \
    r2[4][2] = C13*mx[3]*sv[7] - S23*mx[2]*sv[8]; \
    r2[0][3]=mx[4]*sv[0]; r2[1][3]=mx[5]*sv[0]; r2[2][3]=mx[6]*sv[0]; r2[3][3]=mx[7]*sv[0]; r2[4][3]=mx[8]*sv[0]; \
    r2[0][4] = C13*mx[5]*sv[1] - S23*mx[4]*sv[2]; \
    r2[1][4] = CC12*mx[6]*sv[1] - C16*mx[5]*sv[2] - C13*mx[4]*sv[3]; \
    r2[2][4] = CC12*(mx[7]*sv[1] - mx[5]*sv[3]); \
    r2[3][4] = C13*mx[8]*sv[1] + C16*mx[7]*sv[2] - CC12*mx[6]*sv[3]; \
    r2[4][4] = S23*mx[8]*sv[2] - C13*mx[7]*sv[3]; \
    r2[0][5] = S27*(mx[4]*sv[6] + mx[6]*sv[4]) - S37*mx[5]*sv[5]; \
    r2[1][5] = S37*(mx[4]*sv[7] + mx[7]*sv[4]) - C114*(mx[5]*sv[6] + mx[6]*sv[5]); \
    r2[2][5] = S27*(mx[8]*sv[4] + mx[4]*sv[8] - mx[6]*sv[6]) + C114*(mx[7]*sv[5] + mx[5]*sv[7]); \
    r2[3][5] = S37*(mx[8]*sv[5] + mx[5]*sv[8]) - C114*(mx[7]*sv[6] + mx[6]*sv[7]); \
    r2[4][5] = S27*(mx[8]*sv[6] + mx[6]*sv[8]) - S37*mx[7]*sv[7];

// ---------------- kernel A: vmp + node-CG + wn mix -> mixed[256][72] -------
__global__ void k_nodes(const float* __restrict__ adj,
                        const float* __restrict__ v0,
                        const float* __restrict__ v1,
                        const float* __restrict__ v2,
                        const float* __restrict__ wn0,
                        const float* __restrict__ wn1,
                        const float* __restrict__ wn2,
                        float* __restrict__ mixed){
  __shared__ float vb[72];
  int i = blockIdx.x;
  int lane = threadIdx.x;

  // ---- vmp row i: vb[t] = sum_j adj[i,j] * v[j, t] ----
  {
    const float* vp1; int st1;
    if (lane < 8)       { vp1 = v0 + lane;      st1 = 8;  }
    else if (lane < 32) { vp1 = v1 + (lane-8);  st1 = 24; }
    else                { vp1 = v2 + (lane-32); st1 = 40; }
    const float* vp2 = v2 + 32 + lane;   // valid only for lane<8 (t = 64+lane)
    const float* arow = adj + i*NN;
    float a1a = 0.f, a1b = 0.f, a2a = 0.f, a2b = 0.f;
    #pragma unroll 4
    for (int j = 0; j < NN; j += 2){
      float av0 = arow[j], av1 = arow[j+1];
      a1a = fmaf(av0, vp1[j*st1], a1a);
      a1b = fmaf(av1, vp1[(j+1)*st1], a1b);
      if (lane < 8){
        a2a = fmaf(av0, vp2[j*40], a2a);
        a2b = fmaf(av1, vp2[(j+1)*40], a2b);
      }
    }
    vb[lane] = a1a + a1b;
    if (lane < 8) vb[64+lane] = a2a + a2b;
  }
  __syncthreads();

  // ---- per-lane CG(vb_col_c, vb_col_d) ----
  int c = lane >> 3, d = lane & 7;
  float mx[9], sv[9];
  #pragma unroll
  for (int j=0;j<9;j++){ mx[j] = vb[j*8 + c]; sv[j] = vb[j*8 + d]; }
  float r0[3], r1[3][6], r2[5][6];
  CGREL(mx, sv, r0, r1, r2)

  // ---- wn contraction ----
  float a0[8], a1m[3][8], a2m[5][8];
  #pragma unroll
  for (int dp=0;dp<8;dp++){ a0[dp]=0.f;
    #pragma unroll
    for (int M=0;M<3;M++) a1m[M][dp]=0.f;
    #pragma unroll
    for (int M=0;M<5;M++) a2m[M][dp]=0.f;
  }
  #pragma unroll
  for (int k=0;k<3;k++){
    const float* row = wn0 + (k*64 + lane)*8;
    float4 u = *(const float4*)row;
    float4 v = *(const float4*)(row+4);
    float u8[8] = {u.x,u.y,u.z,u.w,v.x,v.y,v.z,v.w};
    #pragma unroll
    for (int dp=0;dp<8;dp++) a0[dp] = fmaf(r0[k], u8[dp], a0[dp]);
  }
  #pragma unroll
  for (int k=0;k<6;k++){
    const float* row = wn1 + (k*64 + lane)*8;
    float4 u = *(const float4*)row;
    float4 v = *(const float4*)(row+4);
    float u8[8] = {u.x,u.y,u.z,u.w,v.x,v.y,v.z,v.w};
    #pragma unroll
    for (int M=0;M<3;M++)
      #pragma unroll
      for (int dp=0;dp<8;dp++) a1m[M][dp] = fmaf(r1[M][k], u8[dp], a1m[M][dp]);
  }
  #pragma unroll
  for (int k=0;k<6;k++){
    const float* row = wn2 + (k*64 + lane)*8;
    float4 u = *(const float4*)row;
    float4 v = *(const float4*)(row+4);
    float u8[8] = {u.x,u.y,u.z,u.w,v.x,v.y,v.z,v.w};
    #pragma unroll
    for (int M=0;M<5;M++)
      #pragma unroll
      for (int dp=0;dp<8;dp++) a2m[M][dp] = fmaf(r2[M][k], u8[dp], a2m[M][dp]);
  }

  // ---- reduce over 64 lanes, write mixed ----
  #pragma unroll
  for (int m=0;m<9;m++){
    #pragma unroll
    for (int dp=0;dp<8;dp++){
      float val = (m==0) ? a0[dp] : (m<4 ? a1m[m-1][dp] : a2m[m-4][dp]);
      val += __shfl_xor(val, 1);
      val += __shfl_xor(val, 2);
      val += __shfl_xor(val, 4);
      val += __shfl_xor(val, 8);
      val += __shfl_xor(val, 16);
      val += __shfl_xor(val, 32);
      if (lane == ((m*8+dp) & 63)) mixed[i*72 + m*8 + dp] = val;
    }
  }
}

// ---------------- kernel B: pairwise CG + wr mix, sum over x ---------------
// R2 mapping (independent waves, consecutive-y blocks), depth-2 wr pipeline.
#define XPW 8

#define LOAD_WR(x, W0, W1, W2) { \
  int pxy = (x)*NN + y; \
  const float* p0 = wr0 + pxy*192 + lane; \
  const float* p1 = wr1 + pxy*384 + lane; \
  const float* p2 = wr2 + pxy*384 + lane; \
  _Pragma("unroll") for (int k=0;k<3;k++) W0[k] = p0[k*64]; \
  _Pragma("unroll") for (int k=0;k<6;k++) W1[k] = p1[k*64]; \
  _Pragma("unroll") for (int k=0;k<6;k++) W2[k] = p2[k*64]; }

#define LOAD_MS(x) { \
  const float* mb = mixed + (x)*72 + cgp; \
  _Pragma("unroll") for (int j=0;j<9;j++) mx[j] = mb[j*8]; \
  int pxy = (x)*NN + y; \
  sv[0] = s0[pxy]; \
  _Pragma("unroll") for (int j=0;j<3;j++) sv[1+j] = s1[pxy*3+j]; \
  _Pragma("unroll") for (int j=0;j<5;j++) sv[4+j] = s2[pxy*5+j]; }

#define DO_FMA(W0, W1, W2) { \
  _Pragma("unroll") for (int k=0;k<3;k++) acc[0] = fmaf(r0[k], W0[k], acc[0]); \
  _Pragma("unroll") for (int k=0;k<6;k++){ \
    acc[1] = fmaf(r1[0][k], W1[k], acc[1]); \
    acc[2] = fmaf(r1[1][k], W1[k], acc[2]); \
    acc[3] = fmaf(r1[2][k], W1[k], acc[3]); \
    acc[4] = fmaf(r2[0][k], W2[k], acc[4]); \
    acc[5] = fmaf(r2[1][k], W2[k], acc[5]); \
    acc[6] = fmaf(r2[2][k], W2[k], acc[6]); \
    acc[7] = fmaf(r2[3][k], W2[k], acc[7]); \
    acc[8] = fmaf(r2[4][k], W2[k], acc[8]); } }

// One pipeline step: issue wr loads for pair xw into WN*, compute CGREL for
// the pair currently in mx/sv, reload mx/sv for pair xm, consume WC*.
#define STEP(xw, WC0, WC1, WC2, WN0, WN1, WN2, xm) { \
  LOAD_WR(xw, WN0, WN1, WN2); \
  float r0[3], r1[3][6], r2[5][6]; \
  CGREL(mx, sv, r0, r1, r2) \
  LOAD_MS(xm); \
  DO_FMA(WC0, WC1, WC2); }

__global__ __launch_bounds__(256) void k_pair(
    const float* __restrict__ mixed,
    const float* __restrict__ s0, const float* __restrict__ s1, const float* __restrict__ s2,
    const float* __restrict__ wr0, const float* __restrict__ wr1, const float* __restrict__ wr2,
    float* __restrict__ vsum){
  int tid = threadIdx.x;
  int lane = tid & 63;
  int w = blockIdx.x*4 + (tid>>6);
  int y = w & (NN-1);
  int xbase = (w >> 8) * XPW;
  int cgp = lane >> 3;
  int xlast = xbase + XPW - 1;

  float acc[9];
  #pragma unroll
  for (int m=0;m<9;m++) acc[m]=0.f;

  float mx[9], sv[9];
  float wA0[3], wA1[6], wA2[6], wB0[3], wB1[6], wB2[6];
  LOAD_MS(xbase);
  LOAD_WR(xbase, wA0, wA1, wA2);

  #pragma unroll
  for (int i=0;i<XPW;i+=2){
    int x1 = xbase + i + 1;
    int x2 = (i+2 < XPW) ? (xbase + i + 2) : xlast;
    STEP(x1, wA0, wA1, wA2, wB0, wB1, wB2, x1);  // pair i   (consumes A, fills B)
    STEP(x2, wB0, wB1, wB2, wA0, wA1, wA2, x2);  // pair i+1 (consumes B, fills A)
  }

  // reduce over cgp groups (lane bits 3..5)
  #pragma unroll
  for (int m=0;m<9;m++){
    float v = acc[m];
    v += __shfl_xor(v, 8);
    v += __shfl_xor(v, 16);
    v += __shfl_xor(v, 32);
    acc[m] = v;
  }
  if (lane < 8){
    #pragma unroll
    for (int m=0;m<9;m++) atomicAdd(&vsum[y*72 + m*8 + lane], acc[m]);
  }
}

// ---------------- kernel C: part sums + normalize + write ------------------
__global__ void k_final(const float* __restrict__ vsum, float* __restrict__ out){
  __shared__ float ps[3];
  int t = threadIdx.x;   // 1024 threads; 18 elements each
  if (t < 3) ps[t] = 0.f;
  __syncthreads();
  float vals[18];
  float p0=0.f, p1=0.f, p2=0.f;
  #pragma unroll
  for (int k=0;k<18;k++){
    int idx = t*18 + k;
    float v = vsum[idx];
    vals[k] = v;
    int mall = (idx >> 3) % 9;
    if (mall == 0) p0 += v; else if (mall < 4) p1 += v; else p2 += v;
  }
  #pragma unroll
  for (int s=1; s<64; s<<=1){
    p0 += __shfl_xor(p0, s);
    p1 += __shfl_xor(p1, s);
    p2 += __shfl_xor(p2, s);
  }
  if ((t & 63) == 0){
    atomicAdd(&ps[0], p0);
    atomicAdd(&ps[1], p1);
    atomicAdd(&ps[2], p2);
  }
  __syncthreads();
  float q0 = ps[0], q1 = ps[1], q2 = ps[2];
  #pragma unroll
  for (int k=0;k<18;k++){
    int idx = t*18 + k;
    int mall = (idx >> 3) % 9;
    float den = (mall == 0) ? q0 : (mall < 4 ? q1 : q2);
    out[idx] = vals[k] / den;
  }
}

extern "C" void kernel_launch(void* const* d_in, const int* in_sizes, int n_in,
                              void* d_out, int out_size, void* d_ws, size_t ws_size,
                              hipStream_t stream) {
  const float* v0  = (const float*)d_in[0];
  const float* v1  = (const float*)d_in[1];
  const float* v2  = (const float*)d_in[2];
  const float* adj = (const float*)d_in[3];
  const float* s0  = (const float*)d_in[4];
  const float* s1  = (const float*)d_in[5];
  const float* s2  = (const float*)d_in[6];
  const float* wn0 = (const float*)d_in[7];
  const float* wn1 = (const float*)d_in[8];
  const float* wn2 = (const float*)d_in[9];
  const float* wr0 = (const float*)d_in[10];
  const float* wr1 = (const float*)d_in[11];
  const float* wr2 = (const float*)d_in[12];
  float* out = (float*)d_out;

  float* ws    = (float*)d_ws;
  float* mixed = ws;            // 18432
  float* vsum  = ws + 18432;    // 18432

  hipMemsetAsync(vsum, 0, 18432*sizeof(float), stream);
  k_nodes<<<NN, 64, 0, stream>>>(adj, v0, v1, v2, wn0, wn1, wn2, mixed);
  k_pair<<<NN*(NN/XPW)/4, 256, 0, stream>>>(mixed, s0, s1, s2, wr0, wr1, wr2, vsum);
  k_final<<<1, 1024, 0, stream>>>(vsum, out);
}

// Round 5
// 83.833 us; speedup vs baseline: 2.2237x; 1.4372x over previous
//
#include <hip/hip_runtime.h>

#define NN 256

// hard-coded CG constants (l<=2), float32
#define C13  0.5773502691896258f   // 1/sqrt(3)
#define C15  0.4472135954999579f   // 1/sqrt(5)
#define CC12 0.7071067811865476f   // 1/sqrt(2)
#define S35  0.7745966692414834f   // sqrt(3/5)
#define S310 0.5477225575051661f   // sqrt(3/10)
#define C110 0.3162277660168379f   // 1/sqrt(10)
#define S25  0.6324555320336759f   // sqrt(2/5)
#define S23  0.8164965809277260f   // sqrt(2/3)
#define C16  0.4082482904638630f   // 1/sqrt(6)
#define S27  0.5345224838248488f   // sqrt(2/7)
#define S37  0.6546536707079771f   // sqrt(3/7)
#define C114 0.2672612419124244f   // 1/sqrt(14)

// Per-lane CG contraction for one (x-column mx[9], y-column sv[9]) pair.
#define CGREL(mx, sv, r0, r1, r2) \
    r0[0] = mx[0]*sv[0]; \
    r0[1] = C13*(mx[1]*sv[3] - mx[2]*sv[2] + mx[3]*sv[1]); \
    r0[2] = C15*(mx[4]*sv[8] - mx[5]*sv[7] + mx[6]*sv[6] - mx[7]*sv[5] + mx[8]*sv[4]); \
    r1[0][0] = mx[0]*sv[1]; r1[1][0] = mx[0]*sv[2]; r1[2][0] = mx[0]*sv[3]; \
    r1[0][1] = mx[1]*sv[0]; r1[1][1] = mx[2]*sv[0]; r1[2][1] = mx[3]*sv[0]; \
    r1[0][2] = CC12*(mx[2]*sv[1] - mx[1]*sv[2]); \
    r1[1][2] = CC12*(mx[3]*sv[1] - mx[1]*sv[3]); \
    r1[2][2] = CC12*(mx[3]*sv[2] - mx[2]*sv[3]); \
    r1[0][3] = S35*mx[3]*sv[4] - S310*mx[2]*sv[5] + C110*mx[1]*sv[6]; \
    r1[1][3] = S310*(mx[3]*sv[5] + mx[1]*sv[7]) - S25*mx[2]*sv[6]; \
    r1[2][3] = S35*mx[1]*sv[8] - S310*mx[2]*sv[7] + C110*mx[3]*sv[6]; \
    r1[0][4] = C110*mx[6]*sv[1] - S310*mx[5]*sv[2] + S35*mx[4]*sv[3]; \
    r1[1][4] = S310*(mx[7]*sv[1] + mx[5]*sv[3]) - S25*mx[6]*sv[2]; \
    r1[2][4] = S35*mx[8]*sv[1] - S310*mx[7]*sv[2] + C110*mx[6]*sv[3]; \
    r1[0][5] = C15*(mx[7]*sv[4] - mx[4]*sv[7]) + S310*(mx[5]*sv[6] - mx[6]*sv[5]); \
    r1[1][5] = S25*(mx[8]*sv[4] - mx[4]*sv[8]) + C110*(mx[5]*sv[7] - mx[7]*sv[5]); \
    r1[2][5] = C15*(mx[8]*sv[5] - mx[5]*sv[8]) + S310*(mx[6]*sv[7] - mx[7]*sv[6]); \
    r2[0][0]=mx[0]*sv[4]; r2[1][0]=mx[0]*sv[5]; r2[2][0]=mx[0]*sv[6]; r2[3][0]=mx[0]*sv[7]; r2[4][0]=mx[0]*sv[8]; \
    r2[0][1] = mx[1]*sv[1]; \
    r2[1][1] = CC12*(mx[2]*sv[1] + mx[1]*sv[2]); \
    r2[2][1] = C16*(mx[3]*sv[1] + mx[1]*sv[3]) + S23*mx[2]*sv[2]; \
    r2[3][1] = CC12*(mx[3]*sv[2] + mx[2]*sv[3]); \
    r2[4][1] = mx[3]*sv[3]; \
    r2[0][2] = S23*mx[2]*sv[4] - C13*mx[1]*sv[5]; \
    r2[1][2] = C13*mx[3]*sv[4] + C16*mx[2]*sv[5] - CC12*mx[1]*sv[6]; \
    r2[2][2] = CC12*(mx[3]*sv[5] - mx[1]*sv[7]); \
    r2[3][2] = CC12*mx[3]*sv[6] - C16*mx[2]*sv[7] - C13*mx[1]*sv[8]; \
    r2[4][2] = C13*mx[3]*sv[7] - S23*mx[2]*sv[8]; \
    r2[0][3]=mx[4]*sv[0]; r2[1][3]=mx[5]*sv[0]; r2[2][3]=mx[6]*sv[0]; r2[3][3]=mx[7]*sv[0]; r2[4][3]=mx[8]*sv[0]; \
    r2[0][4] = C13*mx[5]*sv[1] - S23*mx[4]*sv[2]; \
    r2[1][4] = CC12*mx[6]*sv[1] - C16*mx[5]*sv[2] - C13*mx[4]*sv[3]; \
    r2[2][4] = CC12*(mx[7]*sv[1] - mx[5]*sv[3]); \
    r2[3][4] = C13*mx[8]*sv[1] + C16*mx[7]*sv[2] - CC12*mx[6]*sv[3]; \
    r2[4][4] = S23*mx[8]*sv[2] - C13*mx[7]*sv[3]; \
    r2[0][5] = S27*(mx[4]*sv[6] + mx[6]*sv[4]) - S37*mx[5]*sv[5]; \
    r2[1][5] = S37*(mx[4]*sv[7] + mx[7]*sv[4]) - C114*(mx[5]*sv[6] + mx[6]*sv[5]); \
    r2[2][5] = S27*(mx[8]*sv[4] + mx[4]*sv[8] - mx[6]*sv[6]) + C114*(mx[7]*sv[5] + mx[5]*sv[7]); \
    r2[3][5] = S37*(mx[8]*sv[5] + mx[5]*sv[8]) - C114*(mx[7]*sv[6] + mx[6]*sv[7]); \
    r2[4][5] = S27*(mx[8]*sv[6] + mx[6]*sv[8]) - S37*mx[7]*sv[7];

// ---------------- kernel A: vmp + node-CG + wn mix -> mixed[256][72] -------
// 4 waves split the j-sum; wave 0 does the short CG+wn phase.
__global__ __launch_bounds__(256) void k_nodes(
                        const float* __restrict__ adj,
                        const float* __restrict__ v0,
                        const float* __restrict__ v1,
                        const float* __restrict__ v2,
                        const float* __restrict__ wn0,
                        const float* __restrict__ wn1,
                        const float* __restrict__ wn2,
                        float* __restrict__ mixed){
  __shared__ float part[4][72];
  int i = blockIdx.x;
  int tid = threadIdx.x, wv = tid >> 6, lane = tid & 63;

  // ---- vmp row i, j-range [wv*64, wv*64+64) ----
  {
    const float* vp1; int st1;
    if (lane < 8)       { vp1 = v0 + lane;      st1 = 8;  }
    else if (lane < 32) { vp1 = v1 + (lane-8);  st1 = 24; }
    else                { vp1 = v2 + (lane-32); st1 = 40; }
    const float* vp2 = v2 + 32 + lane;   // valid only for lane<8 (t = 64+lane)
    const float* arow = adj + i*NN;
    int j0 = wv*64;
    float a1a = 0.f, a1b = 0.f, a2a = 0.f, a2b = 0.f;
    #pragma unroll 8
    for (int j = j0; j < j0+64; j += 2){
      float av0 = arow[j], av1 = arow[j+1];
      a1a = fmaf(av0, vp1[j*st1], a1a);
      a1b = fmaf(av1, vp1[(j+1)*st1], a1b);
      if (lane < 8){
        a2a = fmaf(av0, vp2[j*40], a2a);
        a2b = fmaf(av1, vp2[(j+1)*40], a2b);
      }
    }
    part[wv][lane] = a1a + a1b;
    if (lane < 8) part[wv][64+lane] = a2a + a2b;
  }
  __syncthreads();
  if (wv) return;

  // ---- wave 0: reduce partials into part[0][0..71] ----
  {
    float s = part[0][lane] + part[1][lane] + part[2][lane] + part[3][lane];
    float s2 = 0.f;
    if (lane < 8)
      s2 = part[0][64+lane] + part[1][64+lane] + part[2][64+lane] + part[3][64+lane];
    part[0][lane] = s;
    if (lane < 8) part[0][64+lane] = s2;
  }

  // ---- per-lane CG(col c, col d) ----
  int c = lane >> 3, d = lane & 7;
  float mx[9], sv[9];
  #pragma unroll
  for (int j=0;j<9;j++){ mx[j] = part[0][j*8 + c]; sv[j] = part[0][j*8 + d]; }
  float r0[3], r1[3][6], r2[5][6];
  CGREL(mx, sv, r0, r1, r2)

  // ---- wn contraction ----
  float a0[8], a1m[3][8], a2m[5][8];
  #pragma unroll
  for (int dp=0;dp<8;dp++){ a0[dp]=0.f;
    #pragma unroll
    for (int M=0;M<3;M++) a1m[M][dp]=0.f;
    #pragma unroll
    for (int M=0;M<5;M++) a2m[M][dp]=0.f;
  }
  #pragma unroll
  for (int k=0;k<3;k++){
    const float* row = wn0 + (k*64 + lane)*8;
    float4 u = *(const float4*)row;
    float4 v = *(const float4*)(row+4);
    float u8[8] = {u.x,u.y,u.z,u.w,v.x,v.y,v.z,v.w};
    #pragma unroll
    for (int dp=0;dp<8;dp++) a0[dp] = fmaf(r0[k], u8[dp], a0[dp]);
  }
  #pragma unroll
  for (int k=0;k<6;k++){
    const float* row = wn1 + (k*64 + lane)*8;
    float4 u = *(const float4*)row;
    float4 v = *(const float4*)(row+4);
    float u8[8] = {u.x,u.y,u.z,u.w,v.x,v.y,v.z,v.w};
    #pragma unroll
    for (int M=0;M<3;M++)
      #pragma unroll
      for (int dp=0;dp<8;dp++) a1m[M][dp] = fmaf(r1[M][k], u8[dp], a1m[M][dp]);
  }
  #pragma unroll
  for (int k=0;k<6;k++){
    const float* row = wn2 + (k*64 + lane)*8;
    float4 u = *(const float4*)row;
    float4 v = *(const float4*)(row+4);
    float u8[8] = {u.x,u.y,u.z,u.w,v.x,v.y,v.z,v.w};
    #pragma unroll
    for (int M=0;M<5;M++)
      #pragma unroll
      for (int dp=0;dp<8;dp++) a2m[M][dp] = fmaf(r2[M][k], u8[dp], a2m[M][dp]);
  }

  // ---- reduce over 64 lanes, write mixed ----
  #pragma unroll
  for (int m=0;m<9;m++){
    #pragma unroll
    for (int dp=0;dp<8;dp++){
      float val = (m==0) ? a0[dp] : (m<4 ? a1m[m-1][dp] : a2m[m-4][dp]);
      val += __shfl_xor(val, 1);
      val += __shfl_xor(val, 2);
      val += __shfl_xor(val, 4);
      val += __shfl_xor(val, 8);
      val += __shfl_xor(val, 16);
      val += __shfl_xor(val, 32);
      if (lane == ((m*8+dp) & 63)) mixed[i*72 + m*8 + dp] = val;
    }
  }
}

// ---------------- kernel B: pairwise CG + wr mix, sum over x ---------------
// Independent waves, depth-2 wr register pipeline, 128-VGPR budget.
#define XPW 8

#define LOAD_WR(x, W0, W1, W2) { \
  int pxy = (x)*NN + y; \
  const float* p0 = wr0 + pxy*192 + lane; \
  const float* p1 = wr1 + pxy*384 + lane; \
  const float* p2 = wr2 + pxy*384 + lane; \
  _Pragma("unroll") for (int k=0;k<3;k++) W0[k] = p0[k*64]; \
  _Pragma("unroll") for (int k=0;k<6;k++) W1[k] = p1[k*64]; \
  _Pragma("unroll") for (int k=0;k<6;k++) W2[k] = p2[k*64]; }

#define LOAD_MS(x) { \
  const float* mb = mixed + (x)*72 + cgp; \
  _Pragma("unroll") for (int j=0;j<9;j++) mx[j] = mb[j*8]; \
  int pxy = (x)*NN + y; \
  sv[0] = s0[pxy]; \
  _Pragma("unroll") for (int j=0;j<3;j++) sv[1+j] = s1[pxy*3+j]; \
  _Pragma("unroll") for (int j=0;j<5;j++) sv[4+j] = s2[pxy*5+j]; }

#define DO_FMA(W0, W1, W2) { \
  _Pragma("unroll") for (int k=0;k<3;k++) acc[0] = fmaf(r0[k], W0[k], acc[0]); \
  _Pragma("unroll") for (int k=0;k<6;k++){ \
    acc[1] = fmaf(r1[0][k], W1[k], acc[1]); \
    acc[2] = fmaf(r1[1][k], W1[k], acc[2]); \
    acc[3] = fmaf(r1[2][k], W1[k], acc[3]); \
    acc[4] = fmaf(r2[0][k], W2[k], acc[4]); \
    acc[5] = fmaf(r2[1][k], W2[k], acc[5]); \
    acc[6] = fmaf(r2[2][k], W2[k], acc[6]); \
    acc[7] = fmaf(r2[3][k], W2[k], acc[7]); \
    acc[8] = fmaf(r2[4][k], W2[k], acc[8]); } }

#define STEP(xw, WC0, WC1, WC2, WN0, WN1, WN2, xm) { \
  LOAD_WR(xw, WN0, WN1, WN2); \
  float r0[3], r1[3][6], r2[5][6]; \
  CGREL(mx, sv, r0, r1, r2) \
  LOAD_MS(xm); \
  DO_FMA(WC0, WC1, WC2); }

__global__ __launch_bounds__(256, 4) void k_pair(
    const float* __restrict__ mixed,
    const float* __restrict__ s0, const float* __restrict__ s1, const float* __restrict__ s2,
    const float* __restrict__ wr0, const float* __restrict__ wr1, const float* __restrict__ wr2,
    float* __restrict__ vsum){
  int tid = threadIdx.x;
  int lane = tid & 63;
  int w = blockIdx.x*4 + (tid>>6);
  int y = w & (NN-1);
  int xbase = (w >> 8) * XPW;
  int cgp = lane >> 3;
  int xlast = xbase + XPW - 1;

  float acc[9];
  #pragma unroll
  for (int m=0;m<9;m++) acc[m]=0.f;

  float mx[9], sv[9];
  float wA0[3], wA1[6], wA2[6], wB0[3], wB1[6], wB2[6];
  LOAD_MS(xbase);
  LOAD_WR(xbase, wA0, wA1, wA2);

  #pragma unroll
  for (int i=0;i<XPW;i+=2){
    int x1 = xbase + i + 1;
    int x2 = (i+2 < XPW) ? (xbase + i + 2) : xlast;
    STEP(x1, wA0, wA1, wA2, wB0, wB1, wB2, x1);  // pair i   (consumes A, fills B)
    STEP(x2, wB0, wB1, wB2, wA0, wA1, wA2, x2);  // pair i+1 (consumes B, fills A)
  }

  // reduce over cgp groups (lane bits 3..5)
  #pragma unroll
  for (int m=0;m<9;m++){
    float v = acc[m];
    v += __shfl_xor(v, 8);
    v += __shfl_xor(v, 16);
    v += __shfl_xor(v, 32);
    acc[m] = v;
  }
  if (lane < 8){
    #pragma unroll
    for (int m=0;m<9;m++) atomicAdd(&vsum[y*72 + m*8 + lane], acc[m]);
  }
}

// ---------------- kernel C: part sums + normalize + write ------------------
__global__ void k_final(const float* __restrict__ vsum, float* __restrict__ out){
  __shared__ float ps[3];
  int t = threadIdx.x;   // 1024 threads; 18 elements each
  if (t < 3) ps[t] = 0.f;
  __syncthreads();
  float vals[18];
  float p0=0.f, p1=0.f, p2=0.f;
  #pragma unroll
  for (int k=0;k<18;k++){
    int idx = t*18 + k;
    float v = vsum[idx];
    vals[k] = v;
    int mall = (idx >> 3) % 9;
    if (mall == 0) p0 += v; else if (mall < 4) p1 += v; else p2 += v;
  }
  #pragma unroll
  for (int s=1; s<64; s<<=1){
    p0 += __shfl_xor(p0, s);
    p1 += __shfl_xor(p1, s);
    p2 += __shfl_xor(p2, s);
  }
  if ((t & 63) == 0){
    atomicAdd(&ps[0], p0);
    atomicAdd(&ps[1], p1);
    atomicAdd(&ps[2], p2);
  }
  __syncthreads();
  float q0 = ps[0], q1 = ps[1], q2 = ps[2];
  #pragma unroll
  for (int k=0;k<18;k++){
    int idx = t*18 + k;
    int mall = (idx >> 3) % 9;
    float den = (mall == 0) ? q0 : (mall < 4 ? q1 : q2);
    out[idx] = vals[k] / den;
  }
}

extern "C" void kernel_launch(void* const* d_in, const int* in_sizes, int n_in,
                              void* d_out, int out_size, void* d_ws, size_t ws_size,
                              hipStream_t stream) {
  const float* v0  = (const float*)d_in[0];
  const float* v1  = (const float*)d_in[1];
  const float* v2  = (const float*)d_in[2];
  const float* adj = (const float*)d_in[3];
  const float* s0  = (const float*)d_in[4];
  const float* s1  = (const float*)d_in[5];
  const float* s2  = (const float*)d_in[6];
  const float* wn0 = (const float*)d_in[7];
  const float* wn1 = (const float*)d_in[8];
  const float* wn2 = (const float*)d_in[9];
  const float* wr0 = (const float*)d_in[10];
  const float* wr1 = (const float*)d_in[11];
  const float* wr2 = (const float*)d_in[12];
  float* out = (float*)d_out;

  float* ws    = (float*)d_ws;
  float* mixed = ws;            // 18432
  float* vsum  = ws + 18432;    // 18432

  hipMemsetAsync(vsum, 0, 18432*sizeof(float), stream);
  k_nodes<<<NN, 256, 0, stream>>>(adj, v0, v1, v2, wn0, wn1, wn2, mixed);
  k_pair<<<NN*(NN/XPW)/4, 256, 0, stream>>>(mixed, s0, s1, s2, wr0, wr1, wr2, vsum);
  k_final<<<1, 1024, 0, stream>>>(vsum, out);
}